// Round 1
// baseline (600.086 us; speedup 1.0000x reference)
//
#include <hip/hip_runtime.h>

#define NNODE 16384
#define NEDGE 262144
#define DS    384
#define DZ    128
#define NH    12
#define HD    16
#define HC    192     // NH*HD
#define HPQK  144     // NH*4*3
#define HPV   288     // NH*8*3
#define NCAT  1152    // HC*3 + HPQK*2 + HPV
#define FEAT  2144    // 576 + 12*128 + 32 (12 A-cols + 20 pad)
#define SOUT  384

typedef _Float16 f16;
typedef _Float16 f16x8 __attribute__((ext_vector_type(8)));
typedef _Float16 f16x4 __attribute__((ext_vector_type(4)));
typedef float    f32x4v __attribute__((ext_vector_type(4)));

#define AS3(p) ((__attribute__((address_space(3))) void*)(p))
#define AS1(p) ((const __attribute__((address_space(1))) void*)(p))

// ---------------- K0: weight prep (fp32 -> fp16, fold Wpair/bpair through Wo) ---------
__global__ void k_prep(const float* __restrict__ Wq, const float* __restrict__ Wk,
                       const float* __restrict__ Wv, const float* __restrict__ Wqp,
                       const float* __restrict__ Wkp, const float* __restrict__ Wvp,
                       const float* __restrict__ bq, const float* __restrict__ bk,
                       const float* __restrict__ bv, const float* __restrict__ bqp,
                       const float* __restrict__ bkp, const float* __restrict__ bvp,
                       const float* __restrict__ Wb, const float* __restrict__ Wo,
                       const float* __restrict__ Wpair, const float* __restrict__ bpair,
                       f16* __restrict__ Wcat, float* __restrict__ bcat,
                       f16* __restrict__ Wb16, f16* __restrict__ M2)
{
    int t = blockIdx.x * 256 + threadIdx.x;
    const int T0 = NCAT * DS;
    const int T1 = T0 + NCAT;
    const int T2 = T1 + NH * DZ;
    const int T3 = T2 + SOUT * FEAT;
    if (t < T0) {
        int r = t / DS, c = t - r * DS;
        float v;
        if      (r < 192) v = Wq [(r      ) * DS + c];
        else if (r < 384) v = Wk [(r - 192) * DS + c];
        else if (r < 576) v = Wv [(r - 384) * DS + c];
        else if (r < 720) v = Wqp[(r - 576) * DS + c];
        else if (r < 864) v = Wkp[(r - 720) * DS + c];
        else              v = Wvp[(r - 864) * DS + c];
        Wcat[t] = (f16)v;
    } else if (t < T1) {
        int r = t - T0;
        float v;
        if      (r < 192) v = bq [r];
        else if (r < 384) v = bk [r - 192];
        else if (r < 576) v = bv [r - 384];
        else if (r < 720) v = bqp[r - 576];
        else if (r < 864) v = bkp[r - 720];
        else              v = bvp[r - 864];
        bcat[r] = v;
    } else if (t < T2) {
        int q = t - T1;
        Wb16[q] = (f16)Wb[q];
    } else if (t < T3) {
        int q = t - T2;
        int r = q / FEAT, c = q - r * FEAT;
        float v = 0.f;
        if (c < 576) {
            v = Wo[r * 768 + c];
        } else if (c < 2112) {
            int h = (c - 576) >> 7, cc = (c - 576) & 127;
            float acc = 0.f;
            #pragma unroll
            for (int d = 0; d < 16; ++d)
                acc += Wo[r * 768 + 576 + h * 16 + d] * Wpair[(h * 16 + d) * DZ + cc];
            v = acc;
        } else if (c < 2124) {
            int h = c - 2112;
            float acc = 0.f;
            #pragma unroll
            for (int d = 0; d < 16; ++d)
                acc += Wo[r * 768 + 576 + h * 16 + d] * bpair[h * 16 + d];
            v = acc;
        }
        M2[q] = (f16)v;
    }
}

// ---------------- K1: convert s and z to fp16 ----------------
__global__ void k_convert(const float4* __restrict__ s4, const float4* __restrict__ z4,
                          f16* __restrict__ s16, f16* __restrict__ z16)
{
    int t = blockIdx.x * 256 + threadIdx.x;
    const int NS4 = NNODE * DS / 4;
    const int NZ4 = NEDGE * DZ / 4;
    if (t < NS4) {
        float4 v = s4[t];
        f16x4 o = { (f16)v.x, (f16)v.y, (f16)v.z, (f16)v.w };
        *(f16x4*)(s16 + 4 * (size_t)t) = o;
    } else if (t < NS4 + NZ4) {
        int u = t - NS4;
        float4 v = z4[u];
        f16x4 o = { (f16)v.x, (f16)v.y, (f16)v.z, (f16)v.w };
        *(f16x4*)(z16 + 4 * (size_t)u) = o;
    }
}

// ---------------- MFMA GEMM: C[M,N] = A[M,K] * B[N,K]^T + bias[N] ----------------
// 128x128 tile, BK=32, 4 waves (2x2 of 64x64), fp16 in / fp32 out
__global__ __launch_bounds__(256) void k_gemm(const f16* __restrict__ A, const f16* __restrict__ B,
                                              const float* __restrict__ bias, float* __restrict__ C,
                                              int M, int N, int K)
{
    __shared__ __align__(16) f16 As[128 * 32];
    __shared__ __align__(16) f16 Bs[128 * 32];
    const int tid = threadIdx.x;
    const int wave = tid >> 6, lane = tid & 63;
    const int bm = blockIdx.x, bn = blockIdx.y;
    const int wm = (wave >> 1) * 64, wn = (wave & 1) * 64;
    f32x4v acc[4][4] = {};
    const int srow = wave * 16 + (lane >> 2);
    const int scol = (lane & 3) * 8;
    const f16* gA0 = A + (size_t)(bm * 128 + srow) * K + scol;
    const f16* gA1 = A + (size_t)(bm * 128 + srow + 64) * K + scol;
    const f16* gB0 = B + (size_t)(bn * 128 + srow) * K + scol;
    const f16* gB1 = B + (size_t)(bn * 128 + srow + 64) * K + scol;
    f16* lA0 = As + wave * 512;
    f16* lA1 = As + (wave + 4) * 512;
    f16* lB0 = Bs + wave * 512;
    f16* lB1 = Bs + (wave + 4) * 512;
    const int fr = lane & 15, fc = (lane >> 4) * 8;
    const int nK = K >> 5;
    for (int kk = 0; kk < nK; ++kk) {
        __syncthreads();   // previous compute done before overwrite
        __builtin_amdgcn_global_load_lds(AS1(gA0), AS3(lA0), 16, 0, 0);
        __builtin_amdgcn_global_load_lds(AS1(gA1), AS3(lA1), 16, 0, 0);
        __builtin_amdgcn_global_load_lds(AS1(gB0), AS3(lB0), 16, 0, 0);
        __builtin_amdgcn_global_load_lds(AS1(gB1), AS3(lB1), 16, 0, 0);
        gA0 += 32; gA1 += 32; gB0 += 32; gB1 += 32;
        __syncthreads();   // drains vmcnt -> LDS ready
        f16x8 af[4], bf[4];
        #pragma unroll
        for (int mi = 0; mi < 4; ++mi)
            af[mi] = *(const f16x8*)(As + (wm + mi * 16 + fr) * 32 + fc);
        #pragma unroll
        for (int ni = 0; ni < 4; ++ni)
            bf[ni] = *(const f16x8*)(Bs + (wn + ni * 16 + fr) * 32 + fc);
        #pragma unroll
        for (int mi = 0; mi < 4; ++mi)
            #pragma unroll
            for (int ni = 0; ni < 4; ++ni)
                acc[mi][ni] = __builtin_amdgcn_mfma_f32_16x16x32_f16(af[mi], bf[ni], acc[mi][ni], 0, 0, 0);
    }
    const int r0 = bm * 128 + wm + (lane >> 4) * 4;
    const int c0 = bn * 128 + wn + (lane & 15);
    #pragma unroll
    for (int mi = 0; mi < 4; ++mi)
        #pragma unroll
        for (int ni = 0; ni < 4; ++ni) {
            int col = c0 + ni * 16;
            float b = bias[col];
            #pragma unroll
            for (int r = 0; r < 4; ++r) {
                int row = r0 + mi * 16 + r;
                C[(size_t)row * N + col] = acc[mi][ni][r] + b;
            }
        }
}

// ---------------- K3: split node GEMM output; rotate points to global frame --------
__global__ __launch_bounds__(64) void k_nodepost(const float* __restrict__ raw, const float* __restrict__ fmat,
        float* __restrict__ Q, float* __restrict__ Kf, f16* __restrict__ V16,
        float* __restrict__ QP, float* __restrict__ KP, f16* __restrict__ VP16)
{
    int n = blockIdx.x, l = threadIdx.x;
    const float* r = raw + (size_t)n * NCAT;
    #pragma unroll
    for (int q = 0; q < 3; ++q) {
        int c = q * 64 + l;
        Q [(size_t)n * HC + c] = r[c];
        Kf[(size_t)n * HC + c] = r[HC + c];
        V16[(size_t)n * HC + c] = (f16)r[2 * HC + c];
    }
    const float* fp = fmat + (size_t)n * 16;
    float R00 = fp[0], R01 = fp[1], R02 = fp[2],  t0 = fp[3];
    float R10 = fp[4], R11 = fp[5], R12 = fp[6],  t1 = fp[7];
    float R20 = fp[8], R21 = fp[9], R22 = fp[10], t2 = fp[11];
    if (l < 48) {
        const float* p = r + 576 + 3 * l;
        float x = p[0], y = p[1], zz = p[2];
        QP[(size_t)n * HPQK + 3 * l + 0] = R00 * x + R01 * y + R02 * zz + t0;
        QP[(size_t)n * HPQK + 3 * l + 1] = R10 * x + R11 * y + R12 * zz + t1;
        QP[(size_t)n * HPQK + 3 * l + 2] = R20 * x + R21 * y + R22 * zz + t2;
        const float* p2 = r + 720 + 3 * l;
        float x2 = p2[0], y2 = p2[1], z2 = p2[2];
        KP[(size_t)n * HPQK + 3 * l + 0] = R00 * x2 + R01 * y2 + R02 * z2 + t0;
        KP[(size_t)n * HPQK + 3 * l + 1] = R10 * x2 + R11 * y2 + R12 * z2 + t1;
        KP[(size_t)n * HPQK + 3 * l + 2] = R20 * x2 + R21 * y2 + R22 * z2 + t2;
    }
    {
        const float* p = r + 864 + 3 * l;
        float x = p[0], y = p[1], zz = p[2];
        VP16[(size_t)n * HPV + 3 * l + 0] = (f16)(R00 * x + R01 * y + R02 * zz + t0);
        VP16[(size_t)n * HPV + 3 * l + 1] = (f16)(R10 * x + R11 * y + R12 * zz + t1);
        VP16[(size_t)n * HPV + 3 * l + 2] = (f16)(R20 * x + R21 * y + R22 * zz + t2);
    }
    if (l < 32) {
        int tt = 64 + l;
        const float* p = r + 864 + 3 * tt;
        float x = p[0], y = p[1], zz = p[2];
        VP16[(size_t)n * HPV + 3 * tt + 0] = (f16)(R00 * x + R01 * y + R02 * zz + t0);
        VP16[(size_t)n * HPV + 3 * tt + 1] = (f16)(R10 * x + R11 * y + R12 * zz + t1);
        VP16[(size_t)n * HPV + 3 * tt + 2] = (f16)(R20 * x + R21 * y + R22 * zz + t2);
    }
}

// ---------------- CSR build ----------------
__global__ void k_zero(int* counts, int* cursor) {
    int t = blockIdx.x * 256 + threadIdx.x;
    if (t < NNODE) counts[t] = 0;
    else if (t < 2 * NNODE) cursor[t - NNODE] = 0;
}
__global__ void k_count(const int* __restrict__ ei, int* counts) {
    int e = blockIdx.x * 256 + threadIdx.x;
    if (e < NEDGE) atomicAdd(&counts[ei[2 * e]], 1);
}
__global__ void k_scan(const int* __restrict__ counts, int* __restrict__ rowptr) {
    __shared__ int lds[256];
    int t = threadIdx.x;
    const int per = NNODE / 256;
    int s = 0;
    for (int i = 0; i < per; ++i) s += counts[t * per + i];
    lds[t] = s; __syncthreads();
    for (int off = 1; off < 256; off <<= 1) {
        int v = (t >= off) ? lds[t - off] : 0;
        __syncthreads();
        lds[t] += v;
        __syncthreads();
    }
    int run = (t == 0) ? 0 : lds[t - 1];
    for (int i = 0; i < per; ++i) { rowptr[t * per + i] = run; run += counts[t * per + i]; }
    if (t == 255) rowptr[NNODE] = run;
}
__global__ void k_scatter(const int* __restrict__ ei, const int* __restrict__ rowptr,
                          int* cursor, int* __restrict__ eids) {
    int e = blockIdx.x * 256 + threadIdx.x;
    if (e < NEDGE) {
        int i = ei[2 * e];
        int pos = atomicAdd(&cursor[i], 1);
        eids[rowptr[i] + pos] = e;
    }
}

// ---------------- K5: per-(edge,head) attention logits ----------------
__global__ __launch_bounds__(256) void k_logits(const int* __restrict__ ei,
    const float* __restrict__ Q, const float* __restrict__ Kf,
    const float* __restrict__ QP, const float* __restrict__ KP,
    const f16* __restrict__ z16, const f16* __restrict__ Wb16,
    const float* __restrict__ bb, const float* __restrict__ hw,
    float* __restrict__ attn)
{
    int t = blockIdx.x * 256 + threadIdx.x;
    if (t >= NEDGE * NH) return;
    int e = t / NH, h = t - e * NH;
    int i = ei[2 * e], j = ei[2 * e + 1];
    const float4* qi = (const float4*)(Q + (size_t)i * HC + h * HD);
    const float4* kj = (const float4*)(Kf + (size_t)j * HC + h * HD);
    float dot = 0.f;
    #pragma unroll
    for (int q = 0; q < 4; ++q) {
        float4 a = qi[q], b = kj[q];
        dot += a.x * b.x + a.y * b.y + a.z * b.z + a.w * b.w;
    }
    const f16x8* za = (const f16x8*)(z16 + (size_t)e * DZ);
    const f16x8* wa = (const f16x8*)(Wb16 + h * DZ);
    float zb = 0.f;
    #pragma unroll
    for (int q = 0; q < 16; ++q) {
        f16x8 zv = za[q], wv = wa[q];
        #pragma unroll
        for (int u = 0; u < 8; ++u) zb += (float)zv[u] * (float)wv[u];
    }
    const float4* qp = (const float4*)(QP + (size_t)i * HPQK + h * 12);
    const float4* kp = (const float4*)(KP + (size_t)j * HPQK + h * 12);
    float pt = 0.f;
    #pragma unroll
    for (int q = 0; q < 3; ++q) {
        float4 a = qp[q], b = kp[q];
        float dx = a.x - b.x, dy = a.y - b.y, dz = a.z - b.z, dw = a.w - b.w;
        pt += dx * dx + dy * dy + dz * dz + dw * dw;
    }
    float sp = log1pf(__expf(hw[h]));
    attn[t] = dot * 6.92820323f + (zb + bb[h]) * 1.73205081f + sp * (-3.67423461f) * pt;
}

// ---------------- K6: per-node softmax + aggregation (1 wave / node) ----------------
__global__ __launch_bounds__(64) void k_agg(const int* __restrict__ rowptr, const int* __restrict__ eids,
    const int* __restrict__ ei, const float* __restrict__ attn,
    const f16* __restrict__ z16, const f16* __restrict__ V16, const f16* __restrict__ VP16,
    const float* __restrict__ fmat, f16* __restrict__ feat)
{
    int n = blockIdx.x, l = threadIdx.x;
    int base = rowptr[n], end = rowptr[n + 1];
    float m[NH];
    #pragma unroll
    for (int h = 0; h < NH; ++h) m[h] = -1e30f;
    for (int k = base; k < end; ++k) {
        int e = eids[k];
        const float* ar = attn + (size_t)e * NH;
        #pragma unroll
        for (int h = 0; h < NH; ++h) m[h] = fmaxf(m[h], ar[h]);
    }
    float ls[NH] = {}, u0[NH] = {}, u1[NH] = {};
    float o0 = 0, o1 = 0, o2 = 0;
    float pa0 = 0, pa1 = 0, pa2 = 0, pb0 = 0, pb1 = 0, pb2 = 0;
    const int hA = l >> 4, hB = (64 + l) >> 4, hC2 = (128 + l) >> 4;
    const int h0 = l >> 3, h1 = (64 + l) >> 3;
    for (int k = base; k < end; ++k) {
        int e = eids[k];
        int j = ei[2 * e + 1];
        const float* ar = attn + (size_t)e * NH;
        float ex[NH];
        #pragma unroll
        for (int h = 0; h < NH; ++h) { ex[h] = __expf(ar[h] - m[h]); ls[h] += ex[h]; }
        float zl0 = (float)z16[(size_t)e * DZ + l];
        float zl1 = (float)z16[(size_t)e * DZ + 64 + l];
        #pragma unroll
        for (int h = 0; h < NH; ++h) { u0[h] += ex[h] * zl0; u1[h] += ex[h] * zl1; }
        const f16* vr = V16 + (size_t)j * HC;
        o0 += ex[hA]  * (float)vr[l];
        o1 += ex[hB]  * (float)vr[64 + l];
        o2 += ex[hC2] * (float)vr[128 + l];
        const f16* vp = VP16 + (size_t)j * HPV;
        float ea = ex[h0];
        pa0 += ea * (float)vp[3 * l];
        pa1 += ea * (float)vp[3 * l + 1];
        pa2 += ea * (float)vp[3 * l + 2];
        if (l < 32) {
            float eb = ex[h1];
            pb0 += eb * (float)vp[3 * (64 + l)];
            pb1 += eb * (float)vp[3 * (64 + l) + 1];
            pb2 += eb * (float)vp[3 * (64 + l) + 2];
        }
    }
    float il[NH];
    #pragma unroll
    for (int h = 0; h < NH; ++h) il[h] = (ls[h] > 0.f) ? 1.0f / ls[h] : 0.f;
    f16* fo = feat + (size_t)n * FEAT;
    fo[l]       = (f16)(o0 * il[hA]);
    fo[64 + l]  = (f16)(o1 * il[hB]);
    fo[128 + l] = (f16)(o2 * il[hC2]);
    const float* fp = fmat + (size_t)n * 16;
    float R00 = fp[0], R01 = fp[1], R02 = fp[2],  t0 = fp[3];
    float R10 = fp[4], R11 = fp[5], R12 = fp[6],  t1 = fp[7];
    float R20 = fp[8], R21 = fp[9], R22 = fp[10], t2 = fp[11];
    {
        float gx = pa0 * il[h0] - t0, gy = pa1 * il[h0] - t1, gz = pa2 * il[h0] - t2;
        float lx = R00 * gx + R10 * gy + R20 * gz;
        float ly = R01 * gx + R11 * gy + R21 * gz;
        float lz = R02 * gx + R12 * gy + R22 * gz;
        fo[192 + 3 * l] = (f16)lx; fo[192 + 3 * l + 1] = (f16)ly; fo[192 + 3 * l + 2] = (f16)lz;
        fo[480 + l] = (f16)sqrtf(lx * lx + ly * ly + lz * lz + 1e-8f);
    }
    if (l < 32) {
        int tt = 64 + l;
        float gx = pb0 * il[h1] - t0, gy = pb1 * il[h1] - t1, gz = pb2 * il[h1] - t2;
        float lx = R00 * gx + R10 * gy + R20 * gz;
        float ly = R01 * gx + R11 * gy + R21 * gz;
        float lz = R02 * gx + R12 * gy + R22 * gz;
        fo[192 + 3 * tt] = (f16)lx; fo[192 + 3 * tt + 1] = (f16)ly; fo[192 + 3 * tt + 2] = (f16)lz;
        fo[480 + tt] = (f16)sqrtf(lx * lx + ly * ly + lz * lz + 1e-8f);
    }
    #pragma unroll
    for (int h = 0; h < NH; ++h) {
        fo[576 + h * DZ + l]      = (f16)(u0[h] * il[h]);
        fo[576 + h * DZ + 64 + l] = (f16)(u1[h] * il[h]);
    }
    if (l < 32) fo[2112 + l] = (f16)((l < 12 && end > base) ? 1.0f : 0.0f);
}

extern "C" void kernel_launch(void* const* d_in, const int* in_sizes, int n_in,
                              void* d_out, int out_size, void* d_ws, size_t ws_size,
                              hipStream_t stream)
{
    (void)in_sizes; (void)n_in; (void)out_size; (void)ws_size;
    const float* s     = (const float*)d_in[0];
    const float* z     = (const float*)d_in[1];
    const float* fmat  = (const float*)d_in[2];
    const int*   ei    = (const int*)d_in[3];
    const float* Wq    = (const float*)d_in[4];
    const float* bq    = (const float*)d_in[5];
    const float* Wk    = (const float*)d_in[6];
    const float* bk    = (const float*)d_in[7];
    const float* Wv    = (const float*)d_in[8];
    const float* bv    = (const float*)d_in[9];
    const float* Wb    = (const float*)d_in[10];
    const float* bb    = (const float*)d_in[11];
    const float* Wqp   = (const float*)d_in[12];
    const float* bqp   = (const float*)d_in[13];
    const float* Wkp   = (const float*)d_in[14];
    const float* bkp   = (const float*)d_in[15];
    const float* Wvp   = (const float*)d_in[16];
    const float* bvp   = (const float*)d_in[17];
    const float* hw    = (const float*)d_in[18];
    const float* Wpair = (const float*)d_in[19];
    const float* bpair = (const float*)d_in[20];
    const float* Wo    = (const float*)d_in[21];
    const float* bo    = (const float*)d_in[22];

    // ---- workspace partition ----
    char* w = (char*)d_ws;
    auto alloc = [&](size_t bytes) { char* p = w; w += (bytes + 255) & ~(size_t)255; return p; };
    f16*   s16    = (f16*)  alloc((size_t)NNODE * DS * 2);
    f16*   Wcat   = (f16*)  alloc((size_t)NCAT * DS * 2);
    float* bcat   = (float*)alloc((size_t)NCAT * 4);
    f16*   Wb16   = (f16*)  alloc((size_t)NH * DZ * 2);
    f16*   M2     = (f16*)  alloc((size_t)SOUT * FEAT * 2);
    float* Kb     = (float*)alloc((size_t)NNODE * HC * 4);
    int*   counts = (int*)  alloc((size_t)NNODE * 4);
    int*   rowptr = (int*)  alloc((size_t)(NNODE + 1) * 4);
    int*   cursor = (int*)  alloc((size_t)NNODE * 4);
    int*   eids   = (int*)  alloc((size_t)NEDGE * 4);
    char*  U      = w;                       // union: nodeRaw (75.5MB) then feat (70.3MB)
    float* nodeRaw = (float*)U;
    f16*   feat    = (f16*)U;

    // ---- park transients in the d_out z-region (overwritten by final z copy) ----
    float* zout = (float*)d_out + (size_t)NNODE * DS;
    char*  zr   = (char*)zout;
    f16*   z16  = (f16*)zr;    zr += (size_t)NEDGE * DZ * 2;
    float* attn = (float*)zr;  zr += (size_t)NEDGE * NH * 4;
    float* Qb   = (float*)zr;  zr += (size_t)NNODE * HC * 4;
    float* QPb  = (float*)zr;  zr += (size_t)NNODE * HPQK * 4;
    float* KPb  = (float*)zr;  zr += (size_t)NNODE * HPQK * 4;
    f16*   V16  = (f16*)zr;    zr += (size_t)NNODE * HC * 2;
    f16*   VP16 = (f16*)zr;    // total 126.9MB <= 134.2MB region

    const int PREP_T = NCAT * DS + NCAT + NH * DZ + SOUT * FEAT;
    k_prep<<<(PREP_T + 255) / 256, 256, 0, stream>>>(Wq, Wk, Wv, Wqp, Wkp, Wvp,
        bq, bk, bv, bqp, bkp, bvp, Wb, Wo, Wpair, bpair, Wcat, bcat, Wb16, M2);
    k_convert<<<(NNODE * DS / 4 + NEDGE * DZ / 4) / 256, 256, 0, stream>>>(
        (const float4*)s, (const float4*)z, s16, z16);
    k_gemm<<<dim3(NNODE / 128, NCAT / 128), 256, 0, stream>>>(s16, Wcat, bcat, nodeRaw,
        NNODE, NCAT, DS);
    k_nodepost<<<NNODE, 64, 0, stream>>>(nodeRaw, fmat, Qb, Kb, V16, QPb, KPb, VP16);
    k_zero<<<(2 * NNODE) / 256, 256, 0, stream>>>(counts, cursor);
    k_count<<<NEDGE / 256, 256, 0, stream>>>(ei, counts);
    k_scan<<<1, 256, 0, stream>>>(counts, rowptr);
    k_scatter<<<NEDGE / 256, 256, 0, stream>>>(ei, rowptr, cursor, eids);
    k_logits<<<(NEDGE * NH) / 256, 256, 0, stream>>>(ei, Qb, Kb, QPb, KPb, z16, Wb16, bb, hw, attn);
    k_agg<<<NNODE, 64, 0, stream>>>(rowptr, eids, ei, attn, z16, V16, VP16, fmat, feat);
    hipMemcpyAsync(zout, z, (size_t)NEDGE * DZ * 4, hipMemcpyDeviceToDevice, stream);
    k_gemm<<<dim3(NNODE / 128, SOUT / 128), 256, 0, stream>>>(feat, M2, bo, (float*)d_out,
        NNODE, SOUT, FEAT);
}